// Round 5
// baseline (452.753 us; speedup 1.0000x reference)
//
#include <hip/hip_runtime.h>
#include <hip/hip_bf16.h>

// LinearPreMix: qkv = x @ W_qkv^T, split to q,k,v, reshape [B,S,E]->[B,H,S,DK]
// Pass 1: cast x,W fp32->bf16 into d_ws.
// Pass 2: 256x256 8-phase counted-vmcnt bf16 MFMA GEMM.
// r5: ds_read prefetch-by-1-phase (double frag sets) so LDS latency hides
//     under the previous phase's MFMAs; uniform W_V6 at odd phases; wrapped
//     tail staging keeps vmcnt accounting uniform; vmcnt(0) drain pre-epilogue.

constexpr int Bb = 4, Ss = 4096, Ee = 2048, Hh = 16, Dk = 128;
constexpr int Mm = Bb * Ss;   // 16384
constexpr int Nn = 3 * Ee;    // 6144
constexpr int Kk = Ee;        // 2048

typedef __bf16 bf16_t;
typedef __bf16 bf16x8 __attribute__((ext_vector_type(8)));
typedef float  f32x4  __attribute__((ext_vector_type(4)));

// ---------------------------------------------------------------- cast pass
__global__ __launch_bounds__(256)
void cast_f32_to_bf16(const float* __restrict__ x, const float* __restrict__ w,
                      bf16_t* __restrict__ xb, bf16_t* __restrict__ wb)
{
    const long XG = (long)Mm * Kk / 8;
    const long TG = XG + (long)Nn * Kk / 8;
    const long stride = (long)gridDim.x * blockDim.x;
    for (long g = (long)blockIdx.x * blockDim.x + threadIdx.x; g < TG; g += stride) {
        const float* s; bf16_t* d;
        if (g < XG) { s = x + g * 8;        d = xb + g * 8; }
        else        { s = w + (g - XG) * 8; d = wb + (g - XG) * 8; }
        f32x4 lo = *(const f32x4*)s;
        f32x4 hi = *(const f32x4*)(s + 4);
        bf16x8 o;
#pragma unroll
        for (int j = 0; j < 4; ++j) { o[j] = (bf16_t)lo[j]; o[j + 4] = (bf16_t)hi[j]; }
        *(bf16x8*)d = o;
    }
}

// ------------------------------------------------------- 8-phase 256² GEMM
constexpr int BM = 256, BN = 256, BK = 64;
constexpr int NBM = Mm / BM;          // 64
constexpr int NBN = Nn / BN;          // 24
constexpr int NWG = NBM * NBN;        // 1536 (divisible by 8)
constexpr int NITER = (Kk / BK) / 2;  // 16 octets

#define GLL16(GSRC, LDST) \
  __builtin_amdgcn_global_load_lds((const __attribute__((address_space(1))) void*)(GSRC), \
                                   (__attribute__((address_space(3))) void*)(LDST), 16, 0, 0)

#define STAGE_A(BUF, KH, KOFS) do { \
    bf16_t* _d = sA + ((BUF) * 2 + (KH)) * 8192 + wid * 512; \
    GLL16(srcA0 + (KOFS), _d); \
    GLL16(srcA1 + (KOFS), _d + 4096); \
} while (0)

#define STAGE_B(BUF, KH, KOFS) do { \
    bf16_t* _d = sB + ((BUF) * 2 + (KH)) * 8192 + wid * 512; \
    GLL16(srcB0 + (KOFS), _d); \
    GLL16(srcB1 + (KOFS), _d + 4096); \
} while (0)

// LDS->VGPR fragment reads (swizzled addresses, rule #21 pair of the source swizzle)
#define DS_A(DST, BUF, KS, MH) do { \
    _Pragma("unroll") \
    for (int mf = 0; mf < 4; ++mf) { \
        int r = wm * 128 + (MH) * 64 + mf * 16 + (lane & 15); \
        int q = r * 4 + (kc ^ ((r >> 1) & 3)); \
        DST[mf] = *(const bf16x8*)(sA + ((BUF) * 2 + (KS)) * 8192 + q * 8); \
    } \
} while (0)

#define DS_B(DST, BUF, KS) do { \
    _Pragma("unroll") \
    for (int nf = 0; nf < 4; ++nf) { \
        int cr = wn * 64 + nf * 16 + (lane & 15); \
        int q = cr * 4 + (kc ^ ((cr >> 1) & 3)); \
        DST[nf] = *(const bf16x8*)(sB + ((BUF) * 2 + (KS)) * 8192 + q * 8); \
    } \
} while (0)

#define PF_A(AD, BUF, KS, MH)  DS_A(AD, BUF, KS, MH)
#define PF_AB(AD, BD, BUF, KS) do { DS_A(AD, BUF, KS, 0); DS_B(BD, BUF, KS); } while (0)

#define NONE ((void)0)
#define W_V6 asm volatile("s_waitcnt vmcnt(6)" ::: "memory")

// phase: [prefetch next-phase frags][stage][barrier][MFMA on current frags][wait][barrier]
#define PHASE(MH, AS, BS, PF, STG, WT) do { \
    PF; \
    STG; \
    __builtin_amdgcn_sched_barrier(0); \
    __builtin_amdgcn_s_barrier(); \
    __builtin_amdgcn_sched_barrier(0); \
    __builtin_amdgcn_s_setprio(1); \
    _Pragma("unroll") \
    for (int mf = 0; mf < 4; ++mf) { \
        _Pragma("unroll") \
        for (int nf = 0; nf < 4; ++nf) \
            acc[(MH) * 4 + mf][nf] = __builtin_amdgcn_mfma_f32_16x16x32_bf16( \
                AS[mf], BS[nf], acc[(MH) * 4 + mf][nf], 0, 0, 0); \
    } \
    __builtin_amdgcn_s_setprio(0); \
    WT; \
    __builtin_amdgcn_sched_barrier(0); \
    __builtin_amdgcn_s_barrier(); \
} while (0)

// one octet = 2 K-tiles; stages use wrapped offsets so the tail stays uniform
#define OCTET(KB) \
    PHASE(0, a1, b1, PF_A(a0, 0, 0, 1),        STAGE_A(1, 1, ((KB) +  96) & 2047), W_V6); \
    PHASE(1, a0, b1, PF_AB(a1, b0, 0, 1),      STAGE_B(1, 1, ((KB) +  96) & 2047), NONE); \
    PHASE(0, a1, b0, PF_A(a0, 0, 1, 1),        STAGE_A(0, 0, ((KB) + 128) & 2047), W_V6); \
    PHASE(1, a0, b0, PF_AB(a1, b1, 1, 0),      STAGE_B(0, 0, ((KB) + 128) & 2047), NONE); \
    PHASE(0, a1, b1, PF_A(a0, 1, 0, 1),        STAGE_A(0, 1, ((KB) + 160) & 2047), W_V6); \
    PHASE(1, a0, b1, PF_AB(a1, b0, 1, 1),      STAGE_B(0, 1, ((KB) + 160) & 2047), NONE); \
    PHASE(0, a1, b0, PF_A(a0, 1, 1, 1),        STAGE_A(1, 0, ((KB) + 192) & 2047), W_V6); \
    PHASE(1, a0, b0, PF_AB(a1, b1, 0, 0),      STAGE_B(1, 0, ((KB) + 192) & 2047), NONE);

__global__ __launch_bounds__(512, 2)
void qkv_gemm8(const bf16_t* __restrict__ xb, const bf16_t* __restrict__ wb,
               float* __restrict__ out)
{
    extern __shared__ __attribute__((aligned(16))) char smem_raw[];
    bf16_t* sA = (bf16_t*)smem_raw;                 // [2 buf][2 kh][8192]  64 KiB
    bf16_t* sB = (bf16_t*)(smem_raw + 65536);       // [2 buf][2 kh][8192]  64 KiB

    const int tid  = threadIdx.x;
    const int lane = tid & 63;
    const int wid  = tid >> 6;     // 0..7
    const int wm   = wid >> 2;     // 0..1 (128-row half)
    const int wn   = wid & 3;      // 0..3 (64-col quarter)
    const int kc   = lane >> 4;    // frag k-chunk 0..3

    // XCD-bijective swizzle (NWG % 8 == 0)
    int wg = blockIdx.x;
    wg = (wg & 7) * (NWG >> 3) + (wg >> 3);
    const int bm = wg / NBN, bn = wg % NBN;
    const int m0 = bm * BM, n0 = bn * BN;

    // pre-swizzled staging sources (linear LDS dest + swizzled global source)
    const int r0  = tid >> 2;
    const int cl0 = (tid & 3) ^ ((r0 >> 1) & 3);
    const bf16_t* srcA0 = xb + (size_t)(m0 + r0) * Kk + cl0 * 8;
    const bf16_t* srcA1 = srcA0 + (size_t)128 * Kk;
    const bf16_t* srcB0 = wb + (size_t)(n0 + r0) * Kk + cl0 * 8;
    const bf16_t* srcB1 = srcB0 + (size_t)128 * Kk;

    bf16x8 a0[4], a1[4], b0[4], b1[4];
    f32x4 acc[8][4] = {};

    // prologue: stage (0,0),(0,1),(1,0); confirm (0,0); pre-read phase-1 frags
    STAGE_A(0, 0, 0);  STAGE_B(0, 0, 0);
    STAGE_A(0, 1, 32); STAGE_B(0, 1, 32);
    STAGE_A(1, 0, 64); STAGE_B(1, 0, 64);
    asm volatile("s_waitcnt vmcnt(8)" ::: "memory");
    __builtin_amdgcn_s_barrier();
    DS_A(a1, 0, 0, 0);
    DS_B(b1, 0, 0);

#pragma unroll 1
    for (int it = 0; it < NITER; ++it) {
        const int kb = it * 128;
        OCTET(kb)
    }

    // drain in-flight global_load_lds before waves can exit (LDS reuse hazard)
    asm volatile("s_waitcnt vmcnt(0)" ::: "memory");

    // epilogue: block cols span 2 heads (DK=128); per-wave head constant.
    // nt stores, line-contiguous (mh,mf,r,nf) order.
    const int which = n0 >> 11;
    const int hh    = ((n0 & (Ee - 1)) >> 7) + (wn >> 1);
    const int bb    = m0 >> 12;
    const int s0    = (m0 & (Ss - 1)) + wm * 128;
    float* obase = out + (((size_t)(which * Bb + bb) * Hh + hh) * Ss + s0) * Dk + (wn & 1) * 64;

#pragma unroll
    for (int mh = 0; mh < 2; ++mh)
#pragma unroll
        for (int mf = 0; mf < 4; ++mf)
#pragma unroll
            for (int r = 0; r < 4; ++r)
#pragma unroll
                for (int nf = 0; nf < 4; ++nf) {
                    const int row = mh * 64 + mf * 16 + (lane >> 4) * 4 + r;
                    const int col = nf * 16 + (lane & 15);
                    __builtin_nontemporal_store(acc[mh * 4 + mf][nf][r],
                                                &obase[(size_t)row * Dk + col]);
                }
}

// ------------------------------------------- fallback (fp32 reg staging)
constexpr int FTM = 128, FTN = 128, FTK = 64;
constexpr int FNKT = Kk / FTK;

__global__ __launch_bounds__(256, 2)
void qkv_gemm_fb(const float* __restrict__ x, const float* __restrict__ w,
                 float* __restrict__ out)
{
    __shared__ __attribute__((aligned(16))) bf16_t lA[2][FTM * FTK];
    __shared__ __attribute__((aligned(16))) bf16_t lB[2][FTN * FTK];

    const int tid = threadIdx.x, lane = tid & 63, wid = tid >> 6;
    const int wm = wid >> 1, wn = wid & 1;
    const int n0 = blockIdx.x * FTN, m0 = blockIdx.y * FTM;
    f32x4 ra[8], rb[8];

    auto load_regs = [&](int kt) {
        const int k0 = kt * FTK;
#pragma unroll
        for (int i = 0; i < 4; ++i) {
            const int c = tid + i * 256, row = c >> 3, cir = c & 7;
            const float* pa = x + (size_t)(m0 + row) * Kk + k0 + cir * 8;
            const float* pb = w + (size_t)(n0 + row) * Kk + k0 + cir * 8;
            ra[i*2+0] = *(const f32x4*)(pa); ra[i*2+1] = *(const f32x4*)(pa+4);
            rb[i*2+0] = *(const f32x4*)(pb); rb[i*2+1] = *(const f32x4*)(pb+4);
        }
    };
    auto store_lds = [&](int buf) {
#pragma unroll
        for (int i = 0; i < 4; ++i) {
            const int c = tid + i * 256, row = c >> 3, cir = c & 7;
            const int chunk = row * 8 + (cir ^ (row & 7));
            bf16x8 va, vb;
#pragma unroll
            for (int j = 0; j < 4; ++j) {
                va[j] = (bf16_t)ra[i*2+0][j]; va[j+4] = (bf16_t)ra[i*2+1][j];
                vb[j] = (bf16_t)rb[i*2+0][j]; vb[j+4] = (bf16_t)rb[i*2+1][j];
            }
            *(bf16x8*)(&lA[buf][chunk*8]) = va;
            *(bf16x8*)(&lB[buf][chunk*8]) = vb;
        }
    };
    f32x4 acc[4][4] = {};
    auto compute = [&](int buf) {
#pragma unroll
        for (int ks = 0; ks < 2; ++ks) {
            bf16x8 af[4], bfr[4];
#pragma unroll
            for (int mi = 0; mi < 4; ++mi) {
                const int row = wm*64 + mi*16 + (lane & 15);
                const int cir = ks*4 + (lane >> 4);
                af[mi] = *(const bf16x8*)(&lA[buf][(row*8 + (cir ^ (row & 7)))*8]);
            }
#pragma unroll
            for (int ni = 0; ni < 4; ++ni) {
                const int row = wn*64 + ni*16 + (lane & 15);
                const int cir = ks*4 + (lane >> 4);
                bfr[ni] = *(const bf16x8*)(&lB[buf][(row*8 + (cir ^ (row & 7)))*8]);
            }
#pragma unroll
            for (int mi = 0; mi < 4; ++mi)
#pragma unroll
                for (int ni = 0; ni < 4; ++ni)
                    acc[mi][ni] = __builtin_amdgcn_mfma_f32_16x16x32_bf16(af[mi], bfr[ni], acc[mi][ni], 0, 0, 0);
        }
    };

    load_regs(0); store_lds(0);
    int cur = 0;
#pragma unroll 1
    for (int kt = 0; kt < FNKT; ++kt) {
        __syncthreads();
        if (kt + 1 < FNKT) load_regs(kt + 1);
        compute(cur);
        if (kt + 1 < FNKT) store_lds(cur ^ 1);
        cur ^= 1;
    }
    const int b = m0 / Ss, s0g = m0 % Ss;
    const int which = n0 >> 11, h = (n0 & (Ee - 1)) >> 7;
    float* obase = out + ((size_t)((which * Bb + b) * Hh + h) * Ss + s0g) * Dk;
#pragma unroll
    for (int mi = 0; mi < 4; ++mi)
#pragma unroll
        for (int ni = 0; ni < 4; ++ni)
#pragma unroll
            for (int r = 0; r < 4; ++r) {
                const int rowL = wm*64 + mi*16 + (lane >> 4)*4 + r;
                const int colL = wn*64 + ni*16 + (lane & 15);
                obase[(size_t)rowL * Dk + colL] = acc[mi][ni][r];
            }
}

// ---------------------------------------------------------------- launcher
extern "C" void kernel_launch(void* const* d_in, const int* in_sizes, int n_in,
                              void* d_out, int out_size, void* d_ws, size_t ws_size,
                              hipStream_t stream) {
    const float* x = (const float*)d_in[0];
    const float* w = (const float*)d_in[1];
    float* out = (float*)d_out;

    const size_t xb_bytes = (size_t)Mm * Kk * 2;
    const size_t wb_bytes = (size_t)Nn * Kk * 2;

    if (ws_size >= xb_bytes + wb_bytes) {
        bf16_t* xb = (bf16_t*)d_ws;
        bf16_t* wb = (bf16_t*)((char*)d_ws + xb_bytes);
        cast_f32_to_bf16<<<2048, 256, 0, stream>>>(x, w, xb, wb);
        hipFuncSetAttribute((const void*)qkv_gemm8,
                            hipFuncAttributeMaxDynamicSharedMemorySize, 131072);
        qkv_gemm8<<<NWG, 512, 131072, stream>>>(xb, wb, out);
    } else {
        dim3 grid(Nn / FTN, Mm / FTM);
        qkv_gemm_fb<<<grid, dim3(256), 0, stream>>>(x, w, out);
    }
}

// Round 6
// 440.398 us; speedup vs baseline: 1.0281x; 1.0281x over previous
//
#include <hip/hip_runtime.h>
#include <hip/hip_bf16.h>

// LinearPreMix: qkv = x @ W_qkv^T, split to q,k,v, reshape [B,S,E]->[B,H,S,DK]
// Pass 1: cast x,W fp32->bf16 into d_ws.
// Pass 2: 256x256 8-phase counted-vmcnt bf16 MFMA GEMM.
// r6: L2-cooperative block mapping — each XCD owns a fixed 8-row bm stripe,
//     walks bn-major (bm = xcd*8 + (i&7), bn = i>>3). Co-resident blocks per
//     XCD share 8 A-panels + 4 B-panels in barrier-paced K-lockstep -> L2-hit
//     staging. Otherwise identical to r5 (prefetch-by-1, W_V6, nt epilogue).

constexpr int Bb = 4, Ss = 4096, Ee = 2048, Hh = 16, Dk = 128;
constexpr int Mm = Bb * Ss;   // 16384
constexpr int Nn = 3 * Ee;    // 6144
constexpr int Kk = Ee;        // 2048

typedef __bf16 bf16_t;
typedef __bf16 bf16x8 __attribute__((ext_vector_type(8)));
typedef float  f32x4  __attribute__((ext_vector_type(4)));

// ---------------------------------------------------------------- cast pass
__global__ __launch_bounds__(256)
void cast_f32_to_bf16(const float* __restrict__ x, const float* __restrict__ w,
                      bf16_t* __restrict__ xb, bf16_t* __restrict__ wb)
{
    const long XG = (long)Mm * Kk / 8;
    const long TG = XG + (long)Nn * Kk / 8;
    const long stride = (long)gridDim.x * blockDim.x;
    for (long g = (long)blockIdx.x * blockDim.x + threadIdx.x; g < TG; g += stride) {
        const float* s; bf16_t* d;
        if (g < XG) { s = x + g * 8;        d = xb + g * 8; }
        else        { s = w + (g - XG) * 8; d = wb + (g - XG) * 8; }
        f32x4 lo = *(const f32x4*)s;
        f32x4 hi = *(const f32x4*)(s + 4);
        bf16x8 o;
#pragma unroll
        for (int j = 0; j < 4; ++j) { o[j] = (bf16_t)lo[j]; o[j + 4] = (bf16_t)hi[j]; }
        *(bf16x8*)d = o;
    }
}

// ------------------------------------------------------- 8-phase 256² GEMM
constexpr int BM = 256, BN = 256, BK = 64;
constexpr int NBM = Mm / BM;          // 64
constexpr int NBN = Nn / BN;          // 24
constexpr int NWG = NBM * NBN;        // 1536
constexpr int NITER = (Kk / BK) / 2;  // 16 octets

#define GLL16(GSRC, LDST) \
  __builtin_amdgcn_global_load_lds((const __attribute__((address_space(1))) void*)(GSRC), \
                                   (__attribute__((address_space(3))) void*)(LDST), 16, 0, 0)

#define STAGE_A(BUF, KH, KOFS) do { \
    bf16_t* _d = sA + ((BUF) * 2 + (KH)) * 8192 + wid * 512; \
    GLL16(srcA0 + (KOFS), _d); \
    GLL16(srcA1 + (KOFS), _d + 4096); \
} while (0)

#define STAGE_B(BUF, KH, KOFS) do { \
    bf16_t* _d = sB + ((BUF) * 2 + (KH)) * 8192 + wid * 512; \
    GLL16(srcB0 + (KOFS), _d); \
    GLL16(srcB1 + (KOFS), _d + 4096); \
} while (0)

// LDS->VGPR fragment reads (swizzled addresses, pair of the source swizzle)
#define DS_A(DST, BUF, KS, MH) do { \
    _Pragma("unroll") \
    for (int mf = 0; mf < 4; ++mf) { \
        int r = wm * 128 + (MH) * 64 + mf * 16 + (lane & 15); \
        int q = r * 4 + (kc ^ ((r >> 1) & 3)); \
        DST[mf] = *(const bf16x8*)(sA + ((BUF) * 2 + (KS)) * 8192 + q * 8); \
    } \
} while (0)

#define DS_B(DST, BUF, KS) do { \
    _Pragma("unroll") \
    for (int nf = 0; nf < 4; ++nf) { \
        int cr = wn * 64 + nf * 16 + (lane & 15); \
        int q = cr * 4 + (kc ^ ((cr >> 1) & 3)); \
        DST[nf] = *(const bf16x8*)(sB + ((BUF) * 2 + (KS)) * 8192 + q * 8); \
    } \
} while (0)

#define PF_A(AD, BUF, KS, MH)  DS_A(AD, BUF, KS, MH)
#define PF_AB(AD, BD, BUF, KS) do { DS_A(AD, BUF, KS, 0); DS_B(BD, BUF, KS); } while (0)

#define NONE ((void)0)
#define W_V6 asm volatile("s_waitcnt vmcnt(6)" ::: "memory")

// phase: [prefetch next-phase frags][stage][barrier][MFMA on current frags][wait][barrier]
#define PHASE(MH, AS, BS, PF, STG, WT) do { \
    PF; \
    STG; \
    __builtin_amdgcn_sched_barrier(0); \
    __builtin_amdgcn_s_barrier(); \
    __builtin_amdgcn_sched_barrier(0); \
    __builtin_amdgcn_s_setprio(1); \
    _Pragma("unroll") \
    for (int mf = 0; mf < 4; ++mf) { \
        _Pragma("unroll") \
        for (int nf = 0; nf < 4; ++nf) \
            acc[(MH) * 4 + mf][nf] = __builtin_amdgcn_mfma_f32_16x16x32_bf16( \
                AS[mf], BS[nf], acc[(MH) * 4 + mf][nf], 0, 0, 0); \
    } \
    __builtin_amdgcn_s_setprio(0); \
    WT; \
    __builtin_amdgcn_sched_barrier(0); \
    __builtin_amdgcn_s_barrier(); \
} while (0)

// one octet = 2 K-tiles; stages use wrapped offsets so the tail stays uniform
#define OCTET(KB) \
    PHASE(0, a1, b1, PF_A(a0, 0, 0, 1),        STAGE_A(1, 1, ((KB) +  96) & 2047), W_V6); \
    PHASE(1, a0, b1, PF_AB(a1, b0, 0, 1),      STAGE_B(1, 1, ((KB) +  96) & 2047), NONE); \
    PHASE(0, a1, b0, PF_A(a0, 0, 1, 1),        STAGE_A(0, 0, ((KB) + 128) & 2047), W_V6); \
    PHASE(1, a0, b0, PF_AB(a1, b1, 1, 0),      STAGE_B(0, 0, ((KB) + 128) & 2047), NONE); \
    PHASE(0, a1, b1, PF_A(a0, 1, 0, 1),        STAGE_A(0, 1, ((KB) + 160) & 2047), W_V6); \
    PHASE(1, a0, b1, PF_AB(a1, b0, 1, 1),      STAGE_B(0, 1, ((KB) + 160) & 2047), NONE); \
    PHASE(0, a1, b0, PF_A(a0, 1, 1, 1),        STAGE_A(1, 0, ((KB) + 192) & 2047), W_V6); \
    PHASE(1, a0, b0, PF_AB(a1, b1, 0, 0),      STAGE_B(1, 0, ((KB) + 192) & 2047), NONE);

__global__ __launch_bounds__(512, 2)
void qkv_gemm8(const bf16_t* __restrict__ xb, const bf16_t* __restrict__ wb,
               float* __restrict__ out)
{
    extern __shared__ __attribute__((aligned(16))) char smem_raw[];
    bf16_t* sA = (bf16_t*)smem_raw;                 // [2 buf][2 kh][8192]  64 KiB
    bf16_t* sB = (bf16_t*)(smem_raw + 65536);       // [2 buf][2 kh][8192]  64 KiB

    const int tid  = threadIdx.x;
    const int lane = tid & 63;
    const int wid  = tid >> 6;     // 0..7
    const int wm   = wid >> 2;     // 0..1 (128-row half)
    const int wn   = wid & 3;      // 0..3 (64-col quarter)
    const int kc   = lane >> 4;    // frag k-chunk 0..3

    // r6: L2-cooperative mapping. Each XCD (blk&7) owns bm stripe xcd*8..+8,
    // walks bn-major: co-resident 32 blocks/XCD span 8 A-panels x 4 B-panels,
    // K-lockstep keeps the live slice well inside 4 MiB L2. Bijective:
    // xcd in [0,8) x (i&7) in [0,8) x (i>>3) in [0,24) covers all 64x24 tiles.
    const int xcd = blockIdx.x & 7;
    const int i   = blockIdx.x >> 3;       // 0..191
    const int bm  = xcd * 8 + (i & 7);     // fixed stripe per XCD
    const int bn  = i >> 3;                // 0..23
    const int m0 = bm * BM, n0 = bn * BN;

    // pre-swizzled staging sources (linear LDS dest + swizzled global source)
    const int r0  = tid >> 2;
    const int cl0 = (tid & 3) ^ ((r0 >> 1) & 3);
    const bf16_t* srcA0 = xb + (size_t)(m0 + r0) * Kk + cl0 * 8;
    const bf16_t* srcA1 = srcA0 + (size_t)128 * Kk;
    const bf16_t* srcB0 = wb + (size_t)(n0 + r0) * Kk + cl0 * 8;
    const bf16_t* srcB1 = srcB0 + (size_t)128 * Kk;

    bf16x8 a0[4], a1[4], b0[4], b1[4];
    f32x4 acc[8][4] = {};

    // prologue: stage (0,0),(0,1),(1,0); confirm (0,0); pre-read phase-1 frags
    STAGE_A(0, 0, 0);  STAGE_B(0, 0, 0);
    STAGE_A(0, 1, 32); STAGE_B(0, 1, 32);
    STAGE_A(1, 0, 64); STAGE_B(1, 0, 64);
    asm volatile("s_waitcnt vmcnt(8)" ::: "memory");
    __builtin_amdgcn_s_barrier();
    DS_A(a1, 0, 0, 0);
    DS_B(b1, 0, 0);

#pragma unroll 1
    for (int it = 0; it < NITER; ++it) {
        const int kb = it * 128;
        OCTET(kb)
    }

    // drain in-flight global_load_lds before waves can exit (LDS reuse hazard)
    asm volatile("s_waitcnt vmcnt(0)" ::: "memory");

    // epilogue: block cols span 2 heads (DK=128); per-wave head constant.
    // nt stores, line-contiguous (mh,mf,r,nf) order.
    const int which = n0 >> 11;
    const int hh    = ((n0 & (Ee - 1)) >> 7) + (wn >> 1);
    const int bb    = m0 >> 12;
    const int s0    = (m0 & (Ss - 1)) + wm * 128;
    float* obase = out + (((size_t)(which * Bb + bb) * Hh + hh) * Ss + s0) * Dk + (wn & 1) * 64;

#pragma unroll
    for (int mh = 0; mh < 2; ++mh)
#pragma unroll
        for (int mf = 0; mf < 4; ++mf)
#pragma unroll
            for (int r = 0; r < 4; ++r)
#pragma unroll
                for (int nf = 0; nf < 4; ++nf) {
                    const int row = mh * 64 + mf * 16 + (lane >> 4) * 4 + r;
                    const int col = nf * 16 + (lane & 15);
                    __builtin_nontemporal_store(acc[mh * 4 + mf][nf][r],
                                                &obase[(size_t)row * Dk + col]);
                }
}

// ------------------------------------------- fallback (fp32 reg staging)
constexpr int FTM = 128, FTN = 128, FTK = 64;
constexpr int FNKT = Kk / FTK;

__global__ __launch_bounds__(256, 2)
void qkv_gemm_fb(const float* __restrict__ x, const float* __restrict__ w,
                 float* __restrict__ out)
{
    __shared__ __attribute__((aligned(16))) bf16_t lA[2][FTM * FTK];
    __shared__ __attribute__((aligned(16))) bf16_t lB[2][FTN * FTK];

    const int tid = threadIdx.x, lane = tid & 63, wid = tid >> 6;
    const int wm = wid >> 1, wn = wid & 1;
    const int n0 = blockIdx.x * FTN, m0 = blockIdx.y * FTM;
    f32x4 ra[8], rb[8];

    auto load_regs = [&](int kt) {
        const int k0 = kt * FTK;
#pragma unroll
        for (int i = 0; i < 4; ++i) {
            const int c = tid + i * 256, row = c >> 3, cir = c & 7;
            const float* pa = x + (size_t)(m0 + row) * Kk + k0 + cir * 8;
            const float* pb = w + (size_t)(n0 + row) * Kk + k0 + cir * 8;
            ra[i*2+0] = *(const f32x4*)(pa); ra[i*2+1] = *(const f32x4*)(pa+4);
            rb[i*2+0] = *(const f32x4*)(pb); rb[i*2+1] = *(const f32x4*)(pb+4);
        }
    };
    auto store_lds = [&](int buf) {
#pragma unroll
        for (int i = 0; i < 4; ++i) {
            const int c = tid + i * 256, row = c >> 3, cir = c & 7;
            const int chunk = row * 8 + (cir ^ (row & 7));
            bf16x8 va, vb;
#pragma unroll
            for (int j = 0; j < 4; ++j) {
                va[j] = (bf16_t)ra[i*2+0][j]; va[j+4] = (bf16_t)ra[i*2+1][j];
                vb[j] = (bf16_t)rb[i*2+0][j]; vb[j+4] = (bf16_t)rb[i*2+1][j];
            }
            *(bf16x8*)(&lA[buf][chunk*8]) = va;
            *(bf16x8*)(&lB[buf][chunk*8]) = vb;
        }
    };
    f32x4 acc[4][4] = {};
    auto compute = [&](int buf) {
#pragma unroll
        for (int ks = 0; ks < 2; ++ks) {
            bf16x8 af[4], bfr[4];
#pragma unroll
            for (int mi = 0; mi < 4; ++mi) {
                const int row = wm*64 + mi*16 + (lane & 15);
                const int cir = ks*4 + (lane >> 4);
                af[mi] = *(const bf16x8*)(&lA[buf][(row*8 + (cir ^ (row & 7)))*8]);
            }
#pragma unroll
            for (int ni = 0; ni < 4; ++ni) {
                const int row = wn*64 + ni*16 + (lane & 15);
                const int cir = ks*4 + (lane >> 4);
                bfr[ni] = *(const bf16x8*)(&lB[buf][(row*8 + (cir ^ (row & 7)))*8]);
            }
#pragma unroll
            for (int mi = 0; mi < 4; ++mi)
#pragma unroll
                for (int ni = 0; ni < 4; ++ni)
                    acc[mi][ni] = __builtin_amdgcn_mfma_f32_16x16x32_bf16(af[mi], bfr[ni], acc[mi][ni], 0, 0, 0);
        }
    };

    load_regs(0); store_lds(0);
    int cur = 0;
#pragma unroll 1
    for (int kt = 0; kt < FNKT; ++kt) {
        __syncthreads();
        if (kt + 1 < FNKT) load_regs(kt + 1);
        compute(cur);
        if (kt + 1 < FNKT) store_lds(cur ^ 1);
        cur ^= 1;
    }
    const int b = m0 / Ss, s0g = m0 % Ss;
    const int which = n0 >> 11, h = (n0 & (Ee - 1)) >> 7;
    float* obase = out + ((size_t)((which * Bb + b) * Hh + h) * Ss + s0g) * Dk;
#pragma unroll
    for (int mi = 0; mi < 4; ++mi)
#pragma unroll
        for (int ni = 0; ni < 4; ++ni)
#pragma unroll
            for (int r = 0; r < 4; ++r) {
                const int rowL = wm*64 + mi*16 + (lane >> 4)*4 + r;
                const int colL = wn*64 + ni*16 + (lane & 15);
                obase[(size_t)rowL * Dk + colL] = acc[mi][ni][r];
            }
}

// ---------------------------------------------------------------- launcher
extern "C" void kernel_launch(void* const* d_in, const int* in_sizes, int n_in,
                              void* d_out, int out_size, void* d_ws, size_t ws_size,
                              hipStream_t stream) {
    const float* x = (const float*)d_in[0];
    const float* w = (const float*)d_in[1];
    float* out = (float*)d_out;

    const size_t xb_bytes = (size_t)Mm * Kk * 2;
    const size_t wb_bytes = (size_t)Nn * Kk * 2;

    if (ws_size >= xb_bytes + wb_bytes) {
        bf16_t* xb = (bf16_t*)d_ws;
        bf16_t* wb = (bf16_t*)((char*)d_ws + xb_bytes);
        cast_f32_to_bf16<<<2048, 256, 0, stream>>>(x, w, xb, wb);
        hipFuncSetAttribute((const void*)qkv_gemm8,
                            hipFuncAttributeMaxDynamicSharedMemorySize, 131072);
        qkv_gemm8<<<NWG, 512, 131072, stream>>>(xb, wb, out);
    } else {
        dim3 grid(Nn / FTN, Mm / FTM);
        qkv_gemm_fb<<<grid, dim3(256), 0, stream>>>(x, w, out);
    }
}